// Round 1
// baseline (77.664 us; speedup 1.0000x reference)
//
#include <hip/hip_runtime.h>
#include <math.h>

#define Bsz 8
#define Kc 4
#define Nn 16
#define Ss 64
#define Hh 512
#define F2 1024   // 2H = per-part K dim

__device__ __forceinline__ float logsigf(float x) {
    // log_sigmoid(x) = min(x,0) - log1p(exp(-|x|))  (matches jax.nn.log_sigmoid)
    return fminf(x, 0.0f) - log1pf(expf(-fabsf(x)));
}

// ---------------- GEMM: T = seg_text @ W1[:1024], V = vid @ W1[1024:] ----------------
// z=0: A = seg_text (512 x 1024), B = W1 rows [0,1024)
// z=1: A = vid      (512 x 1024), B = W1 rows [1024,2048)
// Out (512 x 512). Tile 64x64, 256 threads, 4x4 microtile, BK=32.
__global__ __launch_bounds__(256) void gemm_kernel(
    const float* __restrict__ seg, const float* __restrict__ vid,
    const float* __restrict__ W1,
    float* __restrict__ Atext, float* __restrict__ Avid)
{
    const int z = blockIdx.z;
    const float* __restrict__ Amat = z ? vid : seg;
    const float* __restrict__ Bmat = W1 + (z ? (size_t)F2 * Hh : 0);
    float* __restrict__ Out = z ? Avid : Atext;
    const int r0 = blockIdx.x * 64;
    const int n0 = blockIdx.y * 64;
    __shared__ __align__(16) float As[32][68];  // transposed [k][m], padded
    __shared__ __align__(16) float Bs[32][64];  // [k][n]
    const int t = threadIdx.x;
    const int mt = (t >> 4) << 2;   // 0..60
    const int nt = (t & 15) << 2;   // 0..60
    float acc[4][4] = {{0.f}};
    for (int k0 = 0; k0 < F2; k0 += 32) {
        #pragma unroll
        for (int i = 0; i < 2; ++i) {
            int idx = t + i * 256;
            int row = idx >> 3;            // 0..63
            int k4  = (idx & 7) << 2;      // 0..28
            float4 v = *reinterpret_cast<const float4*>(
                Amat + (size_t)(r0 + row) * F2 + k0 + k4);
            As[k4 + 0][row] = v.x; As[k4 + 1][row] = v.y;
            As[k4 + 2][row] = v.z; As[k4 + 3][row] = v.w;
        }
        #pragma unroll
        for (int i = 0; i < 2; ++i) {
            int idx = t + i * 256;
            int kk = idx >> 4;             // 0..31
            int c4 = (idx & 15) << 2;      // 0..60
            *reinterpret_cast<float4*>(&Bs[kk][c4]) =
                *reinterpret_cast<const float4*>(
                    Bmat + (size_t)(k0 + kk) * Hh + n0 + c4);
        }
        __syncthreads();
        #pragma unroll
        for (int kk = 0; kk < 32; ++kk) {
            float4 a4 = *reinterpret_cast<const float4*>(&As[kk][mt]);
            float4 b4 = *reinterpret_cast<const float4*>(&Bs[kk][nt]);
            float av[4] = {a4.x, a4.y, a4.z, a4.w};
            float bv[4] = {b4.x, b4.y, b4.z, b4.w};
            #pragma unroll
            for (int i2 = 0; i2 < 4; ++i2)
                #pragma unroll
                for (int j2 = 0; j2 < 4; ++j2)
                    acc[i2][j2] = fmaf(av[i2], bv[j2], acc[i2][j2]);
        }
        __syncthreads();
    }
    #pragma unroll
    for (int i = 0; i < 4; ++i) {
        float4 o = make_float4(acc[i][0], acc[i][1], acc[i][2], acc[i][3]);
        *reinterpret_cast<float4*>(Out + (size_t)(r0 + mt + i) * Hh + n0 + nt) = o;
    }
}

// ---------------- combine: logits[b,k,n,s] = sum_h relu(T+V+b1)*w2 + b2 ----------------
// One block per (b,k,n); 4 waves, each wave handles 16 s-values with a full 512-dot.
__global__ __launch_bounds__(256) void combine_kernel(
    const float* __restrict__ Atext, const float* __restrict__ Avid,
    const float* __restrict__ b1, const float* __restrict__ w2,
    const float* __restrict__ b2, float* __restrict__ logits)
{
    const int bkn = blockIdx.x;        // 0..511 = ((b*K)+k)*N+n
    const int b = bkn >> 6;            // / (K*N = 64)
    const int t = threadIdx.x;
    __shared__ float Ab[Hh];
    Ab[t]       = Atext[(size_t)bkn * Hh + t]       + b1[t];
    Ab[t + 256] = Atext[(size_t)bkn * Hh + t + 256] + b1[t + 256];
    __syncthreads();
    const int wave = t >> 6, lane = t & 63;
    const int h0 = lane << 3;
    float abr[8], w2r[8];
    #pragma unroll
    for (int j = 0; j < 8; ++j) { abr[j] = Ab[h0 + j]; w2r[j] = w2[h0 + j]; }
    const float bias2 = b2[0];
    #pragma unroll 4
    for (int i = 0; i < 16; ++i) {
        const int s = wave * 16 + i;
        const float* Crow = Avid + (size_t)(b * Ss + s) * Hh + h0;
        float4 c0 = *reinterpret_cast<const float4*>(Crow);
        float4 c1 = *reinterpret_cast<const float4*>(Crow + 4);
        float cv[8] = {c0.x, c0.y, c0.z, c0.w, c1.x, c1.y, c1.z, c1.w};
        float sum = 0.f;
        #pragma unroll
        for (int j = 0; j < 8; ++j) {
            float h = fmaxf(abr[j] + cv[j], 0.f);
            sum = fmaf(h, w2r[j], sum);
        }
        #pragma unroll
        for (int off = 32; off > 0; off >>= 1) sum += __shfl_xor(sum, off);
        if (lane == 0) logits[(size_t)bkn * Ss + s] = sum + bias2;
    }
}

// ---------------- DP + traceback + argmax + outputs ----------------
// One block per b; wave k handles (b,k). Lane = s (S=64 exactly one wave).
__global__ __launch_bounds__(256) void dp_kernel(
    const float* __restrict__ logits, const float* __restrict__ labels,
    float* __restrict__ out)
{
    const int b = blockIdx.x;
    const int t = threadIdx.x;
    const int k = t >> 6, lane = t & 63;
    __shared__ float lgs[Kc][Nn][Ss];
    __shared__ unsigned long long ch[Kc][Nn];
    __shared__ float bestS[Kc], aggS[Kc];
    __shared__ int alignS[Kc][Nn];
    const float* lg = logits + ((size_t)(b * Kc + k) * Nn) * Ss;
    float L[Nn];
    #pragma unroll
    for (int n = 0; n < Nn; ++n) {
        float v = lg[n * Ss + lane];
        lgs[k][n][lane] = v;
        L[n] = logsigf(v);
    }
    // rows from n=15 down to 0; lane = s
    float arr = -100.0f;
    #pragma unroll
    for (int n = Nn - 1; n >= 0; --n) {
        float c = (n == Nn - 1) ? L[n] : (L[n] + arr);
        bool in_band = (lane >= n) && (lane <= (Ss - Nn) + n);
        float m = in_band ? c : -INFINITY;
        // inclusive suffix max across the wave (clamped-index shfl is always defined)
        #pragma unroll
        for (int off = 1; off < 64; off <<= 1) {
            float o = __shfl(m, min(lane + off, 63));
            m = fmaxf(m, o);
        }
        float row = in_band ? fmaxf(m, -100.0f) : -100.0f;
        float rn = __shfl(row, min(lane + 1, 63));
        if (lane == 63) rn = -1e30f;
        bool choice = in_band && (c >= rn);
        unsigned long long mask = __ballot(choice);
        if (lane == 0) ch[k][n] = mask;
        arr = row;
    }
    if (lane == 0) bestS[k] = arr;   // row_{n=0}[s=0]
    __syncthreads();
    if (lane == 0) {
        #pragma unroll
        for (int n = 0; n < Nn; ++n) alignS[k][n] = 0;
        int node = 0, seg = 0; bool done = false; float agg = 0.f;
        for (int it = 0; it < Nn + Ss; ++it) {
            bool took = !done && ((ch[k][node] >> seg) & 1ull);
            if (took) {
                agg += lgs[k][node][seg];
                alignS[k][node] = seg;
                if (node == Nn - 1) done = true; else node++;
            }
            if (!done) seg = min(seg + 1, Ss - 1);
        }
        aggS[k] = agg;
    }
    __syncthreads();
    if (t == 0) {
        int kb = 0; float bb = bestS[0];
        #pragma unroll
        for (int kk = 1; kk < Kc; ++kk)
            if (bestS[kk] > bb) { bb = bestS[kk]; kb = kk; }
        out[b] = 1.0f / (1.0f + expf(-aggS[kb]));           // probs
        out[Bsz + b] = labels[b];                            // labels passthrough
        #pragma unroll
        for (int n = 0; n < Nn; ++n)
            out[2 * Bsz + b * Nn + n] = (float)alignS[kb][n]; // alignment
    }
}

extern "C" void kernel_launch(void* const* d_in, const int* in_sizes, int n_in,
                              void* d_out, int out_size, void* d_ws, size_t ws_size,
                              hipStream_t stream) {
    const float* seg    = (const float*)d_in[0]; // (8,4,16,1024)
    const float* vid    = (const float*)d_in[1]; // (8,64,1024)
    const float* labels = (const float*)d_in[2]; // (8,)
    const float* W1     = (const float*)d_in[3]; // (2048,512)
    const float* b1     = (const float*)d_in[4]; // (512,)
    const float* w2     = (const float*)d_in[5]; // (512,)
    const float* b2     = (const float*)d_in[6]; // (1,)
    float* out = (float*)d_out;                  // 144 floats

    float* Atext  = (float*)d_ws;                // 512*512
    float* Avid   = Atext + 512 * 512;           // 512*512
    float* logits = Avid + 512 * 512;            // 32768

    dim3 g1(8, 8, 2);
    hipLaunchKernelGGL(gemm_kernel, g1, dim3(256), 0, stream, seg, vid, W1, Atext, Avid);
    hipLaunchKernelGGL(combine_kernel, dim3(512), dim3(256), 0, stream,
                       Atext, Avid, b1, w2, b2, logits);
    hipLaunchKernelGGL(dp_kernel, dim3(Bsz), dim3(256), 0, stream, logits, labels, out);
}

// Round 2
// 66.572 us; speedup vs baseline: 1.1666x; 1.1666x over previous
//
#include <hip/hip_runtime.h>
#include <math.h>

#define Bsz 8
#define Kc 4
#define Nn 16
#define Ss 64
#define Hh 512
#define F2 1024   // 2H = per-part K dim

__device__ __forceinline__ float logsigf(float x) {
    // log_sigmoid(x) = min(x,0) - log1p(exp(-|x|))  (matches jax.nn.log_sigmoid)
    return fminf(x, 0.0f) - log1pf(expf(-fabsf(x)));
}

// ---------------- GEMM with split-K ----------------
// blockIdx.z = z*nsplit + q.  z=0: seg_text @ W1[:1024]; z=1: vid @ W1[1024:].
// Each block computes a 64x64 tile over K-range [q*Kq, (q+1)*Kq) and writes the
// partial product to outbuf + blockIdx.z * 512*512.
// 256 threads, 4x4 microtile, BK=32, double-buffered LDS, 1 barrier/K-step.
__global__ __launch_bounds__(256) void gemm_kernel(
    const float* __restrict__ seg, const float* __restrict__ vid,
    const float* __restrict__ W1, float* __restrict__ outbuf, int nsplit)
{
    const int z = blockIdx.z / nsplit;
    const int q = blockIdx.z % nsplit;
    const int Kq = F2 / nsplit;
    const int kbase = q * Kq;
    const float* __restrict__ Amat = z ? vid : seg;
    const float* __restrict__ Bmat = W1 + (z ? (size_t)F2 * Hh : 0);
    float* __restrict__ Out = outbuf + (size_t)blockIdx.z * (512 * Hh);
    const int r0 = blockIdx.x * 64;
    const int n0 = blockIdx.y * 64;
    __shared__ __align__(16) float As[2][32][68];  // transposed [k][m], padded
    __shared__ __align__(16) float Bs[2][32][64];  // [k][n]
    const int t = threadIdx.x;
    const int mt = (t >> 4) << 2;   // 0..60
    const int nt = (t & 15) << 2;   // 0..60
    const int a_row = t >> 3;       // 0..31 (plus +32 for second half)
    const int a_k4  = (t & 7) << 2; // 0..28
    const int b_kk  = t >> 4;       // 0..15 (plus +16)
    const int b_c4  = (t & 15) << 2;

    float4 ra0, ra1, rb0, rb1;
    auto load_step = [&](int s) {
        const int k0 = kbase + s * 32;
        ra0 = *reinterpret_cast<const float4*>(Amat + (size_t)(r0 + a_row) * F2 + k0 + a_k4);
        ra1 = *reinterpret_cast<const float4*>(Amat + (size_t)(r0 + a_row + 32) * F2 + k0 + a_k4);
        rb0 = *reinterpret_cast<const float4*>(Bmat + (size_t)(k0 + b_kk) * Hh + n0 + b_c4);
        rb1 = *reinterpret_cast<const float4*>(Bmat + (size_t)(k0 + b_kk + 16) * Hh + n0 + b_c4);
    };
    auto write_step = [&](int buf) {
        As[buf][a_k4 + 0][a_row] = ra0.x; As[buf][a_k4 + 1][a_row] = ra0.y;
        As[buf][a_k4 + 2][a_row] = ra0.z; As[buf][a_k4 + 3][a_row] = ra0.w;
        As[buf][a_k4 + 0][a_row + 32] = ra1.x; As[buf][a_k4 + 1][a_row + 32] = ra1.y;
        As[buf][a_k4 + 2][a_row + 32] = ra1.z; As[buf][a_k4 + 3][a_row + 32] = ra1.w;
        *reinterpret_cast<float4*>(&Bs[buf][b_kk][b_c4]) = rb0;
        *reinterpret_cast<float4*>(&Bs[buf][b_kk + 16][b_c4]) = rb1;
    };

    float acc[4][4] = {{0.f}};
    load_step(0);
    write_step(0);
    __syncthreads();
    const int steps = Kq / 32;
    for (int s = 0; s < steps; ++s) {
        const int cur = s & 1;
        if (s + 1 < steps) load_step(s + 1);
        #pragma unroll
        for (int kk = 0; kk < 32; ++kk) {
            float4 a4 = *reinterpret_cast<const float4*>(&As[cur][kk][mt]);
            float4 b4 = *reinterpret_cast<const float4*>(&Bs[cur][kk][nt]);
            float av[4] = {a4.x, a4.y, a4.z, a4.w};
            float bv[4] = {b4.x, b4.y, b4.z, b4.w};
            #pragma unroll
            for (int i2 = 0; i2 < 4; ++i2)
                #pragma unroll
                for (int j2 = 0; j2 < 4; ++j2)
                    acc[i2][j2] = fmaf(av[i2], bv[j2], acc[i2][j2]);
        }
        if (s + 1 < steps) {
            write_step(cur ^ 1);
            __syncthreads();
        }
    }
    #pragma unroll
    for (int i = 0; i < 4; ++i) {
        float4 o = make_float4(acc[i][0], acc[i][1], acc[i][2], acc[i][3]);
        *reinterpret_cast<float4*>(Out + (size_t)(r0 + mt + i) * Hh + n0 + nt) = o;
    }
}

// ---------------- combine: logits[b,kn,s] = w2 . relu(T[b,kn]+V[b,s]+b1) + b2 ----
// Sums the nsplit split-K partials inline.  Block = (b, s-chunk of 8, row-quarter
// of 16).  V rows staged in LDS once per block.  Per-lane h = lane + 64*j.
__global__ __launch_bounds__(256) void combine_kernel(
    const float* __restrict__ Tbuf, const float* __restrict__ b1,
    const float* __restrict__ w2, const float* __restrict__ b2,
    float* __restrict__ logits, int nsplit)
{
    const int bid = blockIdx.x;        // b*32 + sc*4 + rq
    const int b  = bid >> 5;
    const int sc = (bid >> 2) & 7;     // s-chunk (8 s each)
    const int rq = bid & 3;            // 16-row chunk of kn
    const int t = threadIdx.x;
    const int wave = t >> 6, lane = t & 63;
    __shared__ float Vs[8][516];       // padded

    // ---- stage V (sum of vid partials) into LDS ----
    {
        const int s_l = t & 7;
        const int h0  = (t >> 3) << 4; // 0..496
        const float* Vbase = Tbuf + (size_t)nsplit * (512 * Hh);
        float vv[16];
        #pragma unroll
        for (int x = 0; x < 16; ++x) vv[x] = 0.f;
        for (int p = 0; p < nsplit; ++p) {
            const float* row = Vbase + (size_t)p * (512 * Hh)
                             + (size_t)(b * Ss + sc * 8 + s_l) * Hh + h0;
            #pragma unroll
            for (int x4 = 0; x4 < 4; ++x4) {
                float4 v = *reinterpret_cast<const float4*>(row + x4 * 4);
                vv[x4*4+0] += v.x; vv[x4*4+1] += v.y;
                vv[x4*4+2] += v.z; vv[x4*4+3] += v.w;
            }
        }
        #pragma unroll
        for (int x4 = 0; x4 < 4; ++x4)
            *reinterpret_cast<float4*>(&Vs[s_l][h0 + x4 * 4]) =
                make_float4(vv[x4*4+0], vv[x4*4+1], vv[x4*4+2], vv[x4*4+3]);
    }
    float w2r[8], b1r[8];
    #pragma unroll
    for (int j = 0; j < 8; ++j) { w2r[j] = w2[lane + 64*j]; b1r[j] = b1[lane + 64*j]; }
    __syncthreads();
    const float bias2 = b2[0];

    #pragma unroll
    for (int i = 0; i < 4; ++i) {
        const int kn = rq * 16 + wave * 4 + i;       // 0..63
        const int r  = b * 64 + kn;                   // global bkn row
        float tj[8];
        #pragma unroll
        for (int j = 0; j < 8; ++j) tj[j] = b1r[j];
        for (int p = 0; p < nsplit; ++p) {
            const float* row = Tbuf + (size_t)p * (512 * Hh) + (size_t)r * Hh;
            #pragma unroll
            for (int j = 0; j < 8; ++j) tj[j] += row[lane + 64*j];
        }
        #pragma unroll
        for (int s = 0; s < 8; ++s) {
            float sum = 0.f;
            #pragma unroll
            for (int j = 0; j < 8; ++j) {
                float h = tj[j] + Vs[s][lane + 64*j];
                sum = fmaf(fmaxf(h, 0.f), w2r[j], sum);
            }
            #pragma unroll
            for (int off = 32; off > 0; off >>= 1) sum += __shfl_xor(sum, off);
            if (lane == 0) logits[(size_t)r * Ss + sc * 8 + s] = sum + bias2;
        }
    }
}

// ---------------- DP + traceback + argmax + outputs ----------------
__global__ __launch_bounds__(256) void dp_kernel(
    const float* __restrict__ logits, const float* __restrict__ labels,
    float* __restrict__ out)
{
    const int b = blockIdx.x;
    const int t = threadIdx.x;
    const int k = t >> 6, lane = t & 63;
    __shared__ float lgs[Kc][Nn][Ss];
    __shared__ unsigned long long ch[Kc][Nn];
    __shared__ float bestS[Kc], aggS[Kc];
    __shared__ int alignS[Kc][Nn];
    const float* lg = logits + ((size_t)(b * Kc + k) * Nn) * Ss;
    float L[Nn];
    #pragma unroll
    for (int n = 0; n < Nn; ++n) {
        float v = lg[n * Ss + lane];
        lgs[k][n][lane] = v;
        L[n] = logsigf(v);
    }
    float arr = -100.0f;
    #pragma unroll
    for (int n = Nn - 1; n >= 0; --n) {
        float c = (n == Nn - 1) ? L[n] : (L[n] + arr);
        bool in_band = (lane >= n) && (lane <= (Ss - Nn) + n);
        float m = in_band ? c : -INFINITY;
        #pragma unroll
        for (int off = 1; off < 64; off <<= 1) {
            float o = __shfl(m, min(lane + off, 63));
            m = fmaxf(m, o);
        }
        float row = in_band ? fmaxf(m, -100.0f) : -100.0f;
        float rn = __shfl(row, min(lane + 1, 63));
        if (lane == 63) rn = -1e30f;
        bool choice = in_band && (c >= rn);
        unsigned long long mask = __ballot(choice);
        if (lane == 0) ch[k][n] = mask;
        arr = row;
    }
    if (lane == 0) bestS[k] = arr;
    __syncthreads();
    if (lane == 0) {
        #pragma unroll
        for (int n = 0; n < Nn; ++n) alignS[k][n] = 0;
        int node = 0, seg = 0; bool done = false; float agg = 0.f;
        for (int it = 0; it < Nn + Ss; ++it) {
            bool took = !done && ((ch[k][node] >> seg) & 1ull);
            if (took) {
                agg += lgs[k][node][seg];
                alignS[k][node] = seg;
                if (node == Nn - 1) done = true; else node++;
            }
            if (!done) seg = min(seg + 1, Ss - 1);
        }
        aggS[k] = agg;
    }
    __syncthreads();
    if (t == 0) {
        int kb = 0; float bb = bestS[0];
        #pragma unroll
        for (int kk = 1; kk < Kc; ++kk)
            if (bestS[kk] > bb) { bb = bestS[kk]; kb = kk; }
        out[b] = 1.0f / (1.0f + expf(-aggS[kb]));
        out[Bsz + b] = labels[b];
        #pragma unroll
        for (int n = 0; n < Nn; ++n)
            out[2 * Bsz + b * Nn + n] = (float)alignS[kb][n];
    }
}

extern "C" void kernel_launch(void* const* d_in, const int* in_sizes, int n_in,
                              void* d_out, int out_size, void* d_ws, size_t ws_size,
                              hipStream_t stream) {
    const float* seg    = (const float*)d_in[0]; // (8,4,16,1024)
    const float* vid    = (const float*)d_in[1]; // (8,64,1024)
    const float* labels = (const float*)d_in[2]; // (8,)
    const float* W1     = (const float*)d_in[3]; // (2048,512)
    const float* b1     = (const float*)d_in[4]; // (512,)
    const float* w2     = (const float*)d_in[5]; // (512,)
    const float* b2     = (const float*)d_in[6]; // (1,)
    float* out = (float*)d_out;                  // 144 floats

    // pick split-K from available workspace (deterministic per run)
    const size_t part = (size_t)512 * Hh;        // floats per partial matrix
    int nsplit = 4;
    while (nsplit > 1 &&
           ((size_t)(2 * nsplit) * part + 32768) * sizeof(float) > ws_size)
        nsplit >>= 1;

    float* Tbuf   = (float*)d_ws;                       // 2*nsplit partials
    float* logits = Tbuf + (size_t)(2 * nsplit) * part; // 32768 floats

    dim3 g1(8, 8, 2 * nsplit);
    hipLaunchKernelGGL(gemm_kernel, g1, dim3(256), 0, stream, seg, vid, W1, Tbuf, nsplit);
    hipLaunchKernelGGL(combine_kernel, dim3(256), dim3(256), 0, stream,
                       Tbuf, b1, w2, b2, logits, nsplit);
    hipLaunchKernelGGL(dp_kernel, dim3(Bsz), dim3(256), 0, stream, logits, labels, out);
}

// Round 3
// 59.418 us; speedup vs baseline: 1.3071x; 1.1204x over previous
//
#include <hip/hip_runtime.h>
#include <math.h>

#define Bsz 8
#define Kc 4
#define Nn 16
#define Ss 64
#define Hh 512
#define F2 1024   // 2H = per-part K dim

__device__ __forceinline__ float logsigf(float x) {
    // log_sigmoid(x) = min(x,0) - log1p(exp(-|x|))  (matches jax.nn.log_sigmoid)
    return fminf(x, 0.0f) - log1pf(expf(-fabsf(x)));
}

// ---------------- GEMM with split-K ----------------
// blockIdx.z = z*nsplit + q.  z=0: seg_text @ W1[:1024]; z=1: vid @ W1[1024:].
// 64x64 tile, 256 threads, 4x4 microtile, BK=32, double-buffered LDS,
// one barrier per K-step (read buf `cur`, write buf `cur^1` — disjoint).
__global__ __launch_bounds__(256) void gemm_kernel(
    const float* __restrict__ seg, const float* __restrict__ vid,
    const float* __restrict__ W1, float* __restrict__ outbuf, int nsplit)
{
    const int z = blockIdx.z / nsplit;
    const int q = blockIdx.z % nsplit;
    const int Kq = F2 / nsplit;
    const int kbase = q * Kq;
    const float* __restrict__ Amat = z ? vid : seg;
    const float* __restrict__ Bmat = W1 + (z ? (size_t)F2 * Hh : 0);
    float* __restrict__ Out = outbuf + (size_t)blockIdx.z * (512 * Hh);
    const int r0 = blockIdx.x * 64;
    const int n0 = blockIdx.y * 64;
    __shared__ __align__(16) float As[2][32][68];  // transposed [k][m], padded
    __shared__ __align__(16) float Bs[2][32][64];  // [k][n]
    const int t = threadIdx.x;
    const int mt = (t >> 4) << 2;
    const int nt = (t & 15) << 2;
    const int a_row = t >> 3;
    const int a_k4  = (t & 7) << 2;
    const int b_kk  = t >> 4;
    const int b_c4  = (t & 15) << 2;

    float4 ra0, ra1, rb0, rb1;
    auto load_step = [&](int s) {
        const int k0 = kbase + s * 32;
        ra0 = *reinterpret_cast<const float4*>(Amat + (size_t)(r0 + a_row) * F2 + k0 + a_k4);
        ra1 = *reinterpret_cast<const float4*>(Amat + (size_t)(r0 + a_row + 32) * F2 + k0 + a_k4);
        rb0 = *reinterpret_cast<const float4*>(Bmat + (size_t)(k0 + b_kk) * Hh + n0 + b_c4);
        rb1 = *reinterpret_cast<const float4*>(Bmat + (size_t)(k0 + b_kk + 16) * Hh + n0 + b_c4);
    };
    auto write_step = [&](int buf) {
        As[buf][a_k4 + 0][a_row] = ra0.x; As[buf][a_k4 + 1][a_row] = ra0.y;
        As[buf][a_k4 + 2][a_row] = ra0.z; As[buf][a_k4 + 3][a_row] = ra0.w;
        As[buf][a_k4 + 0][a_row + 32] = ra1.x; As[buf][a_k4 + 1][a_row + 32] = ra1.y;
        As[buf][a_k4 + 2][a_row + 32] = ra1.z; As[buf][a_k4 + 3][a_row + 32] = ra1.w;
        *reinterpret_cast<float4*>(&Bs[buf][b_kk][b_c4]) = rb0;
        *reinterpret_cast<float4*>(&Bs[buf][b_kk + 16][b_c4]) = rb1;
    };

    float acc[4][4] = {{0.f}};
    load_step(0);
    write_step(0);
    __syncthreads();
    const int steps = Kq / 32;
    for (int s = 0; s < steps; ++s) {
        const int cur = s & 1;
        if (s + 1 < steps) load_step(s + 1);
        #pragma unroll
        for (int kk = 0; kk < 32; ++kk) {
            float4 a4 = *reinterpret_cast<const float4*>(&As[cur][kk][mt]);
            float4 b4 = *reinterpret_cast<const float4*>(&Bs[cur][kk][nt]);
            float av[4] = {a4.x, a4.y, a4.z, a4.w};
            float bv[4] = {b4.x, b4.y, b4.z, b4.w};
            #pragma unroll
            for (int i2 = 0; i2 < 4; ++i2)
                #pragma unroll
                for (int j2 = 0; j2 < 4; ++j2)
                    acc[i2][j2] = fmaf(av[i2], bv[j2], acc[i2][j2]);
        }
        if (s + 1 < steps) {
            write_step(cur ^ 1);
            __syncthreads();
        }
    }
    #pragma unroll
    for (int i = 0; i < 4; ++i) {
        float4 o = make_float4(acc[i][0], acc[i][1], acc[i][2], acc[i][3]);
        *reinterpret_cast<float4*>(Out + (size_t)(r0 + mt + i) * Hh + n0 + nt) = o;
    }
}

// ---------------- reduce: sum split-K partials -> Tfin (+b1), Vfin ----------------
// 2*512*512 floats / 4 per thread = 131072 float4 threads = 512 blocks x 256.
__global__ __launch_bounds__(256) void reduce_kernel(
    const float* __restrict__ Tbuf, const float* __restrict__ b1,
    float* __restrict__ Tfin, float* __restrict__ Vfin, int nsplit)
{
    const int idx = blockIdx.x * 256 + threadIdx.x;  // 0..131071
    const int half = idx >> 16;                      // 0: text, 1: vid
    const int off4 = idx & 65535;
    const float4* src = reinterpret_cast<const float4*>(Tbuf)
                      + (size_t)half * nsplit * 65536 + off4;
    float4 a = src[0];
    for (int p = 1; p < nsplit; ++p) {
        float4 v = src[(size_t)p * 65536];
        a.x += v.x; a.y += v.y; a.z += v.z; a.w += v.w;
    }
    if (half == 0) {
        const int h = (off4 & 127) << 2;
        a.x += b1[h]; a.y += b1[h + 1]; a.z += b1[h + 2]; a.w += b1[h + 3];
        reinterpret_cast<float4*>(Tfin)[off4] = a;
    } else {
        reinterpret_cast<float4*>(Vfin)[off4] = a;
    }
}

// ---------------- combine: logits[bkn,s] = w2 . relu(Tfin[bkn]+Vfin[b,s]) + b2 ----
// Block = (b, s-chunk of 8, k-quarter).  V rows staged in LDS once per block.
__global__ __launch_bounds__(256) void combine_kernel(
    const float* __restrict__ Tfin, const float* __restrict__ Vfin,
    const float* __restrict__ w2, const float* __restrict__ b2,
    float* __restrict__ logits)
{
    const int bid = blockIdx.x;        // b*32 + sc*4 + rq
    const int b  = bid >> 5;
    const int sc = (bid >> 2) & 7;
    const int rq = bid & 3;
    const int t = threadIdx.x;
    const int wave = t >> 6, lane = t & 63;
    __shared__ float Vs[8][520];
    {
        const int s_l = t & 7;
        const int h0  = (t >> 3) << 4;
        const float* row = Vfin + (size_t)(b * Ss + sc * 8 + s_l) * Hh + h0;
        #pragma unroll
        for (int x4 = 0; x4 < 4; ++x4)
            *reinterpret_cast<float4*>(&Vs[s_l][h0 + 4 * x4]) =
                *reinterpret_cast<const float4*>(row + 4 * x4);
    }
    float w2r[8];
    #pragma unroll
    for (int j = 0; j < 8; ++j) w2r[j] = w2[lane + 64 * j];
    const float bias2 = b2[0];
    __syncthreads();
    #pragma unroll
    for (int i = 0; i < 4; ++i) {
        const int kn = rq * 16 + wave * 4 + i;
        const int r  = b * 64 + kn;
        const float* trow = Tfin + (size_t)r * Hh;
        float tj[8];
        #pragma unroll
        for (int j = 0; j < 8; ++j) tj[j] = trow[lane + 64 * j];
        #pragma unroll
        for (int s = 0; s < 8; ++s) {
            float sum = 0.f;
            #pragma unroll
            for (int j = 0; j < 8; ++j)
                sum = fmaf(fmaxf(tj[j] + Vs[s][lane + 64 * j], 0.f), w2r[j], sum);
            #pragma unroll
            for (int off = 32; off > 0; off >>= 1) sum += __shfl_xor(sum, off);
            if (lane == 0) logits[(size_t)r * Ss + sc * 8 + s] = sum + bias2;
        }
    }
}

// ---------------- DP + register traceback + argmax + outputs ----------------
// One block per b; wave k handles (b,k); lane = s.  Traceback is branch-free
// register math: align[n] = first set bit of mask[n] at >= prev+1 (the serial
// reference walk increments seg every iteration, so "take" = first set bit).
__global__ __launch_bounds__(256) void dp_kernel(
    const float* __restrict__ logits, const float* __restrict__ labels,
    float* __restrict__ out)
{
    const int b = blockIdx.x;
    const int t = threadIdx.x;
    const int k = t >> 6, lane = t & 63;
    const float* lg = logits + (size_t)((b * Kc + k) * Nn) * Ss;
    float lv[Nn], L[Nn];
    #pragma unroll
    for (int n = 0; n < Nn; ++n) {
        lv[n] = lg[n * Ss + lane];
        L[n] = logsigf(lv[n]);
    }
    float arr = -100.0f;
    unsigned long long msk[Nn];
    #pragma unroll
    for (int n = Nn - 1; n >= 0; --n) {
        float c = (n == Nn - 1) ? L[n] : (L[n] + arr);
        bool in_band = (lane >= n) && (lane <= (Ss - Nn) + n);
        float m = in_band ? c : -INFINITY;
        #pragma unroll
        for (int off = 1; off < 64; off <<= 1) {
            float o = __shfl(m, min(lane + off, 63));
            m = fmaxf(m, o);
        }
        float row = in_band ? fmaxf(m, -100.0f) : -100.0f;
        float rn = __shfl(row, min(lane + 1, 63));
        if (lane == 63) rn = -1e30f;
        msk[n] = __ballot(in_band && (c >= rn));
        arr = row;
    }
    const float best = __shfl(arr, 0);
    float agg = 0.f;
    int start = 0;
    int alignv[Nn];
    bool dead = false;
    #pragma unroll
    for (int n = 0; n < Nn; ++n) {
        unsigned long long m2 = dead ? 0ull : (msk[n] & (~0ull << start));
        if (m2) {
            const int s = __builtin_ctzll(m2);
            agg += __shfl(lv[n], s);
            alignv[n] = s;
            start = s + 1;
        } else {
            alignv[n] = 0;
            dead = true;  // reference walk: node never advances again
        }
    }
    __shared__ float bestS[Kc], aggS[Kc];
    __shared__ int alS[Kc][Nn];
    if (lane == 0) {
        bestS[k] = best; aggS[k] = agg;
        #pragma unroll
        for (int n = 0; n < Nn; ++n) alS[k][n] = alignv[n];
    }
    __syncthreads();
    if (t == 0) {
        int kb = 0; float bb = bestS[0];
        #pragma unroll
        for (int kk = 1; kk < Kc; ++kk)
            if (bestS[kk] > bb) { bb = bestS[kk]; kb = kk; }
        out[b] = 1.0f / (1.0f + expf(-aggS[kb]));
        out[Bsz + b] = labels[b];
        #pragma unroll
        for (int n = 0; n < Nn; ++n)
            out[2 * Bsz + b * Nn + n] = (float)alS[kb][n];
    }
}

extern "C" void kernel_launch(void* const* d_in, const int* in_sizes, int n_in,
                              void* d_out, int out_size, void* d_ws, size_t ws_size,
                              hipStream_t stream) {
    const float* seg    = (const float*)d_in[0]; // (8,4,16,1024)
    const float* vid    = (const float*)d_in[1]; // (8,64,1024)
    const float* labels = (const float*)d_in[2]; // (8,)
    const float* W1     = (const float*)d_in[3]; // (2048,512)
    const float* b1     = (const float*)d_in[4]; // (512,)
    const float* w2     = (const float*)d_in[5]; // (512,)
    const float* b2     = (const float*)d_in[6]; // (1,)
    float* out = (float*)d_out;                  // 144 floats

    const size_t part = (size_t)512 * Hh;        // floats per partial matrix
    int nsplit = 8;
    while (nsplit > 1 &&
           ((size_t)(2 * nsplit) * part + 2 * part + 32768) * sizeof(float) > ws_size)
        nsplit >>= 1;

    float* Tbuf   = (float*)d_ws;
    float* Tfin   = Tbuf + (size_t)(2 * nsplit) * part;
    float* Vfin   = Tfin + part;
    float* logits = Vfin + part;

    dim3 g1(8, 8, 2 * nsplit);
    hipLaunchKernelGGL(gemm_kernel, g1, dim3(256), 0, stream, seg, vid, W1, Tbuf, nsplit);
    hipLaunchKernelGGL(reduce_kernel, dim3(512), dim3(256), 0, stream,
                       Tbuf, b1, Tfin, Vfin, nsplit);
    hipLaunchKernelGGL(combine_kernel, dim3(256), dim3(256), 0, stream,
                       Tfin, Vfin, w2, b2, logits);
    hipLaunchKernelGGL(dp_kernel, dim3(Bsz), dim3(256), 0, stream, logits, labels, out);
}